// Round 15
// baseline (110.917 us; speedup 1.0000x reference)
//
#include <hip/hip_runtime.h>

typedef __attribute__((ext_vector_type(2))) float f32x2;
typedef __attribute__((ext_vector_type(4))) float f32x4;
typedef __attribute__((ext_vector_type(8))) __bf16 bf16x8;
typedef __attribute__((ext_vector_type(8))) unsigned short u16x8;
typedef __attribute__((ext_vector_type(4))) unsigned short u16x4;
typedef __attribute__((ext_vector_type(4))) unsigned int u32x4;

#define LOG2E 1.4426950408889634f

// f32 -> bf16 round-to-nearest-even (bit pattern)
__device__ __forceinline__ unsigned short f2bf(float f) {
  unsigned u = __builtin_bit_cast(unsigned, f);
  u += 0x7fffu + ((u >> 16) & 1u);
  return (unsigned short)(u >> 16);
}

// two f32 -> packed 2x bf16 (hardware RNE; low half = first arg)
__device__ __forceinline__ unsigned cvtpk(float lo, float hi) {
  unsigned r;
  asm("v_cvt_pk_bf16_f32 %0, %1, %2" : "=v"(r) : "v"(lo), "v"(hi));
  return r;
}

// packed f32x2 add (VOP3P)
__device__ __forceinline__ f32x2 pkadd(f32x2 a, f32x2 b) {
  f32x2 r;
  asm("v_pk_add_f32 %0, %1, %2" : "=v"(r) : "v"(a), "v"(b));
  return r;
}

// raw v_exp_f32: 2^x, single transcendental instruction (no libm wrapper)
__device__ __forceinline__ float fexp2(float x) {
  float r;
  asm("v_exp_f32 %0, %1" : "=v"(r) : "v"(x));
  return r;
}

__device__ __forceinline__ f32x4 mfma16(bf16x8 a, bf16x8 b, f32x4 c) {
  return __builtin_amdgcn_mfma_f32_16x16x32_bf16(a, b, c, 0, 0, 0);
}

__device__ __forceinline__ void gload_lds16(const void* g, void* l) {
  __builtin_amdgcn_global_load_lds(
      (const __attribute__((address_space(1))) void*)g,
      (__attribute__((address_space(3))) void*)l, 16, 0, 0);
}

// sizes
#define NQK 6291456      // 2*12*4096*64  (one z-slice of qkv, elems)
#define NW 589824        // 768*768

// ---------------------------------------------------------------------------
// Kernel 1: wtrans only. W [768K x 768N] f32 -> Wt [768N x 768K] bf16 (x3)
// ---------------------------------------------------------------------------
__global__ __launch_bounds__(256) void prep_kernel(
    const float* __restrict__ Wq, const float* __restrict__ Wk,
    const float* __restrict__ Wv, unsigned short* __restrict__ Wt) {
  __shared__ float tile[64][65];
  const int bid = blockIdx.x;
  const int t = threadIdx.x;
  const int z = bid / 144, rest = bid % 144;
  const float* __restrict__ src = (z == 0) ? Wq : (z == 1) ? Wk : Wv;
  unsigned short* __restrict__ dst = Wt + (size_t)z * NW;
  const int k0 = (rest / 12) * 64, n0 = (rest % 12) * 64;
  const int r = t >> 4, c4 = (t & 15) * 4;
#pragma unroll
  for (int p = 0; p < 4; ++p) {
    int rr = r + p * 16;
    f32x4 v = *(const f32x4*)(src + (size_t)(k0 + rr) * 768 + n0 + c4);
#pragma unroll
    for (int j = 0; j < 4; ++j) tile[rr][c4 + j] = v[j];
  }
  __syncthreads();
#pragma unroll
  for (int p = 0; p < 4; ++p) {
    int rn = r + p * 16;
    u16x4 o;
#pragma unroll
    for (int j = 0; j < 4; ++j) o[j] = f2bf(tile[c4 + j][rn]);
    *(u16x4*)(dst + (size_t)(n0 + rn) * 768 + k0 + c4) = o;
  }
}

// ---------------------------------------------------------------------------
// Kernel 2: QKV projection reading X in f32 directly (xconv fused).
// A: reg-staged f32->bf16 (T14 async-split: loads at top, cvt+ds_write after
// MFMA under vmcnt(4)); B: gload_lds bf16.  Counted-vmcnt skeleton of R13.
// z=0 -> Q (scaled 0.125*log2e); z=1 -> K; z=2 -> V^T [bh*64+d][s].
// ---------------------------------------------------------------------------
__global__ __launch_bounds__(256) void qkv_gemm_kernel(
    const float* __restrict__ from_t, const float* __restrict__ to_t,
    const unsigned short* __restrict__ Wt,
    const float* __restrict__ bq, const float* __restrict__ bk,
    const float* __restrict__ bv, unsigned short* __restrict__ qkvQK,
    unsigned short* __restrict__ vt) {
  __shared__ unsigned short A_lds[2][8192];  // [128m][64k], chunk-swizzled
  __shared__ unsigned short B_lds[2][8192];  // [128n][64k]
  const int bid0 = blockIdx.x;
  const int bid = (bid0 & 7) * 144 + (bid0 >> 3);  // XCD-contiguous chunks
  const int z = bid / 384;
  const int rem = bid % 384;
  const int bm = rem / 6, bn = rem % 6;
  const float* __restrict__ X = z ? to_t : from_t;
  const unsigned short* __restrict__ Wz = Wt + (size_t)z * NW;
  const float* __restrict__ bias = (z == 0) ? bq : (z == 1) ? bk : bv;
  const int t = threadIdx.x, lane = t & 63, w = t >> 6;
  const int wm = (w >> 1) * 64, wn = (w & 1) * 64;
  const int l15 = lane & 15, cc = lane >> 4;

  f32x4 acc[4][4];
#pragma unroll
  for (int i = 0; i < 4; ++i)
#pragma unroll
    for (int j = 0; j < 4; ++j) acc[i][j] = (f32x4){0.f, 0.f, 0.f, 0.f};

  const unsigned short* Bbase = Wz + (size_t)bn * 128 * 768;

  // A reg-staging geometry: thread t owns chunks {p*256+t}, p=0..3.
  //   chunk ch -> row r = ch>>3 = p*32 + (t>>3), slot sl = t&7,
  //   content col g = sl ^ (r&7)  (r&7 == (t>>3)&7, p*32 multiple of 8)
  const int g_ = (t & 7) ^ ((t >> 3) & 7);
  const float* arow0 = X + (size_t)(bm * 128 + (t >> 3)) * 768 + g_ * 8;

  auto LOAD_A = [&](int ks, f32x4* av) {
#pragma unroll
    for (int p = 0; p < 4; ++p) {
      const float* pp = arow0 + (size_t)p * 32 * 768 + ks * 64;
      av[2 * p] = *(const f32x4*)pp;
      av[2 * p + 1] = *(const f32x4*)(pp + 4);
    }
  };
  auto WRITE_A = [&](int bufi, const f32x4* av) {
    char* dst = (char*)A_lds[bufi] + t * 16;
#pragma unroll
    for (int p = 0; p < 4; ++p) {
      u32x4 wv;
      wv[0] = cvtpk(av[2 * p][0], av[2 * p][1]);
      wv[1] = cvtpk(av[2 * p][2], av[2 * p][3]);
      wv[2] = cvtpk(av[2 * p + 1][0], av[2 * p + 1][1]);
      wv[3] = cvtpk(av[2 * p + 1][2], av[2 * p + 1][3]);
      *(u32x4*)(dst + p * 4096) = wv;
    }
  };
  auto STAGE_B = [&](int ks, int bufi) {
#pragma unroll
    for (int p = 0; p < 4; ++p) {
      int wb = p * 4 + w;            // wave-chunk 0..15 (wave-uniform)
      int ch = wb * 64 + lane;       // 16B chunk 0..1023
      int r = ch >> 3, sl = ch & 7;
      int g = sl ^ (r & 7);
      gload_lds16(Bbase + (size_t)r * 768 + ks * 64 + g * 8,
                  &B_lds[bufi][wb * 512]);
    }
  };

  f32x4 av[8];
  // prologue: tile 0 (A regs + convert + write; B gloads stay in flight)
  LOAD_A(0, av);
  STAGE_B(0, 0);
  asm volatile("s_waitcnt vmcnt(4)" ::: "memory");  // 8 A loads done
  WRITE_A(0, av);

  for (int ks = 0; ks < 12; ++ks) {
    const int cur = ks & 1;
    if (ks < 11) {
      LOAD_A(ks + 1, av);           // 8 f32x4 loads (oldest of new batch)
      STAGE_B(ks + 1, cur ^ 1);     // 4 gloads
      // outstanding = 4 (B of ks) + 12 (new); wait the 4 oldest = B(ks)
      asm volatile("s_waitcnt vmcnt(12) lgkmcnt(0)" ::: "memory");
    } else {
      asm volatile("s_waitcnt vmcnt(0) lgkmcnt(0)" ::: "memory");
    }
    __builtin_amdgcn_s_barrier();   // tile ks fully visible; cur^1 free
    __builtin_amdgcn_sched_barrier(0);

    bf16x8 af[4][2], bfr[4][2];
#pragma unroll
    for (int mi = 0; mi < 4; ++mi) {
      int row = wm + mi * 16 + l15;
      const char* rp = (const char*)A_lds[cur] + row * 128;
#pragma unroll
      for (int kk = 0; kk < 2; ++kk)
        af[mi][kk] = *(const bf16x8*)(rp + (((cc + 4 * kk) ^ (row & 7)) << 4));
    }
#pragma unroll
    for (int ni = 0; ni < 4; ++ni) {
      int row = wn + ni * 16 + l15;
      const char* rp = (const char*)B_lds[cur] + row * 128;
#pragma unroll
      for (int kk = 0; kk < 2; ++kk)
        bfr[ni][kk] = *(const bf16x8*)(rp + (((cc + 4 * kk) ^ (row & 7)) << 4));
    }
#pragma unroll
    for (int kk = 0; kk < 2; ++kk)
#pragma unroll
      for (int mi = 0; mi < 4; ++mi)
#pragma unroll
        for (int ni = 0; ni < 4; ++ni)
          acc[mi][ni] = mfma16(af[mi][kk], bfr[ni][kk], acc[mi][ni]);

    if (ks < 11) {
      // A(ks+1) f32 loads were issued ~700cy ago; B(ks+1) stays in flight
      asm volatile("s_waitcnt vmcnt(4)" ::: "memory");
      WRITE_A(cur ^ 1, av);
      asm volatile("s_waitcnt lgkmcnt(0)" ::: "memory");
      __builtin_amdgcn_s_barrier();  // A(ks+1) visible; reads of cur done
    }
  }

  if (z < 2) {
    const float qscale = (z == 0) ? 0.125f * LOG2E : 1.0f;
    unsigned short* __restrict__ dst = qkvQK + (size_t)z * NQK;
#pragma unroll
    for (int ni = 0; ni < 4; ++ni) {
      int gn = bn * 128 + wn + ni * 16 + l15;
      float bv_ = bias[gn];
      int hh = gn >> 6, dd = gn & 63;
#pragma unroll
      for (int mi = 0; mi < 4; ++mi) {
#pragma unroll
        for (int r = 0; r < 4; ++r) {
          int gm = bm * 128 + wm + mi * 16 + cc * 4 + r;
          int bb = gm >> 12, s = gm & 4095;
          float val = (acc[mi][ni][r] + bv_) * qscale;
          dst[((((size_t)bb * 12 + hh) * 4096 + s) * 64) + dd] = f2bf(val);
        }
      }
    }
  } else {
    // V^T: vt[(bh*64+d)*4096 + s], r-index is s-contiguous -> packed stores
#pragma unroll
    for (int ni = 0; ni < 4; ++ni) {
      int gn = bn * 128 + wn + ni * 16 + l15;
      float bv_ = bias[gn];
      int hh = gn >> 6, dd = gn & 63;
#pragma unroll
      for (int mi = 0; mi < 4; ++mi) {
        int gm0 = bm * 128 + wm + mi * 16 + cc * 4;
        int bb = gm0 >> 12, s0 = gm0 & 4095;
        u16x4 o;
#pragma unroll
        for (int r = 0; r < 4; ++r) o[r] = f2bf(acc[mi][ni][r] + bv_);
        *(u16x4*)(vt + ((size_t)(bb * 12 + hh) * 64 + dd) * 4096 + s0) = o;
      }
    }
  }
}

// ---------------------------------------------------------------------------
// Kernel 3: block-sparse attention. R14 structure (raw v_exp_f32, penalty as
// MFMA C-in, permuted-key PV, software-pipelined QK(ib+1)).  [unchanged]
// ---------------------------------------------------------------------------
__global__ __launch_bounds__(256, 4) void attn_kernel(
    const unsigned short* __restrict__ qkvQK, const unsigned short* __restrict__ vt,
    const int* __restrict__ to_mask, const int* __restrict__ rand_attn,
    float* __restrict__ out, float* __restrict__ part_o,
    float* __restrict__ part_ml) {
  __shared__ unsigned short K_lds[2][4096];   // [64key][64d], src-chunk swizzled
  __shared__ unsigned short VT_lds[2][4096];  // [64d][64key], src-chunk swizzled
  __shared__ float penal[8][64];
  __shared__ int blist[8];

  const int bid0 = blockIdx.x;
  const int bid = (bid0 & 7) * 234 + (bid0 >> 3);  // 234 = 3 (b,h)-groups/XCD
  const int bh = bid / 78, r78 = bid % 78;
  const int h = bh % 12, b = bh / 12;
  const int t = threadIdx.x, lane = t & 63, w = t >> 6;
  const int l15 = lane & 15, cc = lane >> 4;

  int m, nblk, chunk = 0;
  bool full;
  if (r78 < 62) {
    full = false;
    m = r78 + 1;
    nblk = (m == 1 || m == 62) ? 7 : 8;
    if (t == 0) {
      const int* rp = rand_attn + ((size_t)h * 62 + (m - 1)) * 3;
      if (m == 1) {
        blist[0] = 0; blist[1] = 1; blist[2] = 2; blist[3] = 63;
        blist[4] = rp[0]; blist[5] = rp[1]; blist[6] = rp[2];
      } else if (m == 62) {
        blist[0] = 0; blist[1] = 61; blist[2] = 62; blist[3] = 63;
        blist[4] = rp[0]; blist[5] = rp[1]; blist[6] = rp[2];
      } else {
        blist[0] = m - 1; blist[1] = m; blist[2] = m + 1;
        blist[3] = rp[0]; blist[4] = rp[1]; blist[5] = rp[2];
        blist[6] = 0; blist[7] = 63;
      }
    }
  } else {
    full = true;
    int fr = r78 - 62;
    chunk = fr & 7;
    m = (fr >> 3) ? 63 : 0;
    nblk = 8;
    if (t < 8) blist[t] = chunk * 8 + t;
  }

  const unsigned short* qp = qkvQK + (((size_t)b * 12 + h) * 4096 + m * 64) * 64;
  const unsigned short* kp = qkvQK + NQK + (((size_t)b * 12 + h) * 4096) * 64;
  const unsigned short* vtp = vt + (((size_t)b * 12 + h) * 64) * 4096;

  // hoisted per-lane staging constants
  int loff[2];
  const unsigned short *kpl[2], *vpl[2];
#pragma unroll
  for (int p = 0; p < 2; ++p) {
    int wb = p * 4 + w;            // wave-chunk (wave-uniform)
    int ch = wb * 64 + lane;       // 16B chunk id
    int rr = ch >> 3;
    int g = (ch & 7) ^ (rr & 7);   // source-chunk XOR permutation
    loff[p] = wb * 512;
    kpl[p] = kp + rr * 64 + g * 8;
    vpl[p] = vtp + rr * 4096 + g * 8;
  }

  // V^T b64 read base (bytes within one VT buffer), loop-invariant.
  int vaddr[4];
#pragma unroll
  for (int dg = 0; dg < 4; ++dg) {
    int d = dg * 16 + l15;
    vaddr[dg] = d * 128 + ((((cc >> 1) ^ (d & 7)) << 4)) + (cc & 1) * 8;
  }

  // Q as B-operand: col = q = l15, k = d  (log2e*0.125 folded in)
  bf16x8 aq[2];
  {
    int qrow = w * 16 + l15;
    aq[0] = *(const bf16x8*)(qp + qrow * 64 + cc * 8);
    aq[1] = *(const bf16x8*)(qp + qrow * 64 + 32 + cc * 8);
  }

  float m_run = -INFINITY, l_run = 0.f;  // per-lane state for q = w*16 + l15
  f32x4 o_acc[4];                        // q = cc*4+r, d = dg*16+l15
#pragma unroll
  for (int dg = 0; dg < 4; ++dg) o_acc[dg] = (f32x4){0.f, 0.f, 0.f, 0.f};

  auto STAGE_K = [&](int kb, int bufi) {
    const size_t ko = (size_t)kb * 4096;
    gload_lds16(kpl[0] + ko, &K_lds[bufi][loff[0]]);
    gload_lds16(kpl[1] + ko, &K_lds[bufi][loff[1]]);
  };
  auto STAGE_V = [&](int kb, int bufi) {
    const size_t vo = (size_t)kb * 64;
    gload_lds16(vpl[0] + vo, &VT_lds[bufi][loff[0]]);
    gload_lds16(vpl[1] + vo, &VT_lds[bufi][loff[1]]);
  };

  // QK of a tile (K in buffer bufi), penalty folded as MFMA C-in -> s[][]
  auto QK = [&](int bufi, int slot, float s[4][4]) {
    const char* kbase = (const char*)K_lds[bufi];
    __builtin_amdgcn_s_setprio(1);
#pragma unroll
    for (int kg = 0; kg < 4; ++kg) {
      int krow = kg * 16 + l15;
      const char* rp = kbase + krow * 128;
      int sz = (krow & 7) << 4;
      bf16x8 k0 = *(const bf16x8*)(rp + ((cc << 4) ^ sz));
      bf16x8 k1 = *(const bf16x8*)(rp + (((cc + 4) << 4) ^ sz));
      f32x4 pen = *(const f32x4*)(&penal[slot][kg * 16 + cc * 4]);
      f32x4 zz = mfma16(k0, aq[0], pen);  // C-in = penalty (S = K.Q + pen)
      zz = mfma16(k1, aq[1], zz);
#pragma unroll
      for (int r = 0; r < 4; ++r) s[kg][r] = zz[r];
    }
    __builtin_amdgcn_s_setprio(0);
  };

  __syncthreads();  // blist visible (no vmem in flight yet)

  {  // penal preload for the whole block list (log2e-scaled)
    int ib = w;
#pragma unroll
    for (int pp = 0; pp < 2; ++pp, ib += 4)
      if (ib < nblk)
        penal[ib][lane] =
            (1.0f - (float)to_mask[(size_t)b * 4096 + blist[ib] * 64 + lane]) *
            (-1e9f * LOG2E);
  }
  // prefetch: K0, V0, K1.  vmcnt(4): my K0 loads landed; lgkm: penal written.
  STAGE_K(blist[0], 0);
  STAGE_V(blist[0], 0);
  STAGE_K(blist[1], 1);
  asm volatile("s_waitcnt vmcnt(4) lgkmcnt(0)" ::: "memory");
  __builtin_amdgcn_s_barrier();  // everyone's K0 + penal visible
  __builtin_amdgcn_sched_barrier(0);

  float sm[4][4];
  QK(0, 0, sm);  // scores for tile 0 (in flight across loop-top barrier)

  union PF { unsigned u[4]; bf16x8 v; };
  union VF { u16x4 h2[2]; bf16x8 v; };

  for (int ib = 0; ib < nblk; ++ib) {
    // V(ib) and K(ib+1) were issued one full iteration ago -> wait is ~free
    asm volatile("s_waitcnt vmcnt(0)" ::: "memory");
    __builtin_amdgcn_s_barrier();
    __builtin_amdgcn_sched_barrier(0);

    // stage next tiles (after barrier -> buffers proven free)
    if (ib + 2 < nblk) STAGE_K(blist[ib + 2], ib & 1);
    if (ib + 1 < nblk) STAGE_V(blist[ib + 1], (ib + 1) & 1);

    // early QK for tile ib+1 (MFMA pipe; result consumed NEXT iteration)
    float sn[4][4];
    if (ib + 1 < nblk) QK((ib + 1) & 1, ib + 1, sn);

    // ---- softmax for tile ib (VALU pipe, overlaps QK retirement) ----
    float m1 = fmaxf(fmaxf(sm[0][0], sm[0][1]), sm[0][2]);
    float m2 = fmaxf(fmaxf(sm[0][3], sm[1][0]), sm[1][1]);
    float m3 = fmaxf(fmaxf(sm[1][2], sm[1][3]), sm[2][0]);
    float m4 = fmaxf(fmaxf(sm[2][1], sm[2][2]), sm[2][3]);
    float m5 = fmaxf(fmaxf(sm[3][0], sm[3][1]), sm[3][2]);
    float mx = fmaxf(fmaxf(fmaxf(m1, m2), m3),
                     fmaxf(fmaxf(m4, m5), sm[3][3]));
    mx = fmaxf(mx, __shfl_xor(mx, 16, 64));
    mx = fmaxf(mx, __shfl_xor(mx, 32, 64));

    // defer-max: rescale only when max grew by more than THR=8 (P <= 2^8)
    if (!__all(mx - m_run <= 8.0f)) {
      float mn = fmaxf(m_run, mx);
      float fac = fexp2(m_run - mn);
      m_run = mn;
      l_run *= fac;
      float fr_[4];
#pragma unroll
      for (int r = 0; r < 4; ++r) fr_[r] = __shfl(fac, cc * 4 + r, 64);
#pragma unroll
      for (int dg = 0; dg < 4; ++dg)
#pragma unroll
        for (int r = 0; r < 4; ++r) o_acc[dg][r] *= fr_[r];
    }

    // p = 2^(s - m) via raw v_exp_f32: pack + pk_add sum tree
    unsigned pk[8];
    f32x2 ps[8];
#pragma unroll
    for (int kg = 0; kg < 4; ++kg) {
      float p0 = fexp2(sm[kg][0] - m_run), p1 = fexp2(sm[kg][1] - m_run);
      float p2 = fexp2(sm[kg][2] - m_run), p3 = fexp2(sm[kg][3] - m_run);
      pk[kg * 2] = cvtpk(p0, p1);
      pk[kg * 2 + 1] = cvtpk(p2, p3);
      ps[kg * 2] = (f32x2){p0, p1};
      ps[kg * 2 + 1] = (f32x2){p2, p3};
    }
    f32x2 s0 = pkadd(pkadd(ps[0], ps[1]), pkadd(ps[2], ps[3]));
    f32x2 s1 = pkadd(pkadd(ps[4], ps[5]), pkadd(ps[6], ps[7]));
    f32x2 st = pkadd(s0, s1);
    float rs = st[0] + st[1];
    rs += __shfl_xor(rs, 16, 64);
    rs += __shfl_xor(rs, 32, 64);
    l_run += rs;

    // A-frags: permuted-key order => lane's own packs, no data movement
    PF a0, a1;
    a0.u[0] = pk[0]; a0.u[1] = pk[1]; a0.u[2] = pk[2]; a0.u[3] = pk[3];
    a1.u[0] = pk[4]; a1.u[1] = pk[5]; a1.u[2] = pk[6]; a1.u[3] = pk[7];

    // PV: V fragments via 4x ds_read_b64 per dg (same key permutation)
    const char* vbuf = (const char*)VT_lds[ib & 1];
    __builtin_amdgcn_s_setprio(1);
#pragma unroll
    for (int dg = 0; dg < 4; ++dg) {
      int a00 = vaddr[dg];
      VF f0, f1;
      f0.h2[0] = *(const u16x4*)(vbuf + a00);
      f0.h2[1] = *(const u16x4*)(vbuf + (a00 ^ 32));
      f1.h2[0] = *(const u16x4*)(vbuf + (a00 ^ 64));
      f1.h2[1] = *(const u16x4*)(vbuf + (a00 ^ 96));
      o_acc[dg] = mfma16(a0.v, f0.v, o_acc[dg]);
      o_acc[dg] = mfma16(a1.v, f1.v, o_acc[dg]);
    }
    __builtin_amdgcn_s_setprio(0);

    if (ib + 1 < nblk) {
#pragma unroll
      for (int kg = 0; kg < 4; ++kg)
#pragma unroll
        for (int r = 0; r < 4; ++r) sm[kg][r] = sn[kg][r];
    }
  }

  if (!full) {
    float inv[4];
#pragma unroll
    for (int r = 0; r < 4; ++r) inv[r] = 1.0f / __shfl(l_run, cc * 4 + r, 64);
#pragma unroll
    for (int r = 0; r < 4; ++r) {
      int s = m * 64 + w * 16 + cc * 4 + r;
#pragma unroll
      for (int dg = 0; dg < 4; ++dg) {
        int d = dg * 16 + l15;
        out[(((size_t)b * 4096 + s) * 12 + h) * 64 + d] = o_acc[dg][r] * inv[r];
      }
    }
  } else {
    const int row = (b * 12 + h) * 2 + (m ? 1 : 0);
    float* po = part_o + (((size_t)row * 8 + chunk) * 64) * 64;
    float* pml = part_ml + ((size_t)row * 8 + chunk) * 128;
#pragma unroll
    for (int r = 0; r < 4; ++r) {
      int q = w * 16 + cc * 4 + r;
#pragma unroll
      for (int dg = 0; dg < 4; ++dg) {
        int d = dg * 16 + l15;
        po[q * 64 + d] = o_acc[dg][r];
      }
    }
    if (cc == 0) {  // lane l15 holds softmax state (log2 domain) for its q
      pml[w * 16 + l15] = m_run;
      pml[64 + w * 16 + l15] = l_run;
    }
  }
}

// ---------------------------------------------------------------------------
// Kernel 4: merge 8 split-K partials per full row (48 rows), exp2 weights.
// ---------------------------------------------------------------------------
__global__ __launch_bounds__(256) void combine_kernel(
    const float* __restrict__ part_o, const float* __restrict__ part_ml,
    float* __restrict__ out) {
  const int row = blockIdx.x;  // (b*12+h)*2 + (m==63)
  const int b = row / 24, h = (row >> 1) % 12, m = (row & 1) ? 63 : 0;
  const int t = threadIdx.x;
  const int q = t >> 2, d0 = (t & 3) * 16;

  float mc[8], lc[8];
  float M = -INFINITY;
#pragma unroll
  for (int c = 0; c < 8; ++c) {
    const float* pml = part_ml + ((size_t)row * 8 + c) * 128;
    mc[c] = pml[q];
    lc[c] = pml[64 + q];
    M = fmaxf(M, mc[c]);
  }
  float wgt[8], L = 0.f;
#pragma unroll
  for (int c = 0; c < 8; ++c) {
    wgt[c] = fexp2(mc[c] - M);
    L += wgt[c] * lc[c];
  }
  f32x4 acc[4];
#pragma unroll
  for (int j = 0; j < 4; ++j) acc[j] = (f32x4){0.f, 0.f, 0.f, 0.f};
#pragma unroll
  for (int c = 0; c < 8; ++c) {
    const float* po = part_o + (((size_t)row * 8 + c) * 64 + q) * 64 + d0;
#pragma unroll
    for (int j = 0; j < 4; ++j) {
      f32x4 v = *(const f32x4*)(po + j * 4);
#pragma unroll
      for (int e = 0; e < 4; ++e) acc[j][e] += wgt[c] * v[e];
    }
  }
  const float inv = 1.0f / L;
  const int s = m * 64 + q;
  float* op = out + (((size_t)b * 4096 + s) * 12 + h) * 64 + d0;
#pragma unroll
  for (int j = 0; j < 4; ++j) {
    f32x4 v;
#pragma unroll
    for (int e = 0; e < 4; ++e) v[e] = acc[j][e] * inv;
    *(f32x4*)(op + j * 4) = v;
  }
}

// ---------------------------------------------------------------------------
extern "C" void kernel_launch(void* const* d_in, const int* in_sizes, int n_in,
                              void* d_out, int out_size, void* d_ws,
                              size_t ws_size, hipStream_t stream) {
  (void)in_sizes; (void)n_in; (void)out_size; (void)ws_size;
  const float* from_t = (const float*)d_in[0];
  const float* to_t = (const float*)d_in[1];
  const float* Wq = (const float*)d_in[2];
  const float* bq = (const float*)d_in[3];
  const float* Wk = (const float*)d_in[4];
  const float* bk = (const float*)d_in[5];
  const float* Wv = (const float*)d_in[6];
  const float* bv = (const float*)d_in[7];
  const int* to_mask = (const int*)d_in[8];
  const int* rand_attn = (const int*)d_in[9];
  float* out = (float*)d_out;

  // workspace (47.8 MB): Wt | qkvQK (Q,K) | vt (V^T) | part_o | part_ml
  unsigned short* Wt = (unsigned short*)d_ws;
  unsigned short* qkvQK = Wt + (size_t)3 * NW;
  unsigned short* vt = qkvQK + (size_t)2 * NQK;
  float* part_o = (float*)(vt + (size_t)NQK);
  float* part_ml = part_o + (size_t)48 * 8 * 64 * 64;

  prep_kernel<<<dim3(432), dim3(256), 0, stream>>>(Wq, Wk, Wv, Wt);
  qkv_gemm_kernel<<<dim3(1152), dim3(256), 0, stream>>>(
      from_t, to_t, Wt, bq, bk, bv, qkvQK, vt);
  attn_kernel<<<dim3(1872), dim3(256), 0, stream>>>(
      qkvQK, vt, to_mask, rand_attn, out, part_o, part_ml);
  combine_kernel<<<dim3(48), dim3(256), 0, stream>>>(part_o, part_ml, out);
}

// Round 16
// 101.480 us; speedup vs baseline: 1.0930x; 1.0930x over previous
//
#include <hip/hip_runtime.h>

typedef __attribute__((ext_vector_type(2))) float f32x2;
typedef __attribute__((ext_vector_type(4))) float f32x4;
typedef __attribute__((ext_vector_type(8))) __bf16 bf16x8;
typedef __attribute__((ext_vector_type(8))) unsigned short u16x8;
typedef __attribute__((ext_vector_type(4))) unsigned short u16x4;

#define LOG2E 1.4426950408889634f

// f32 -> bf16 round-to-nearest-even (bit pattern)
__device__ __forceinline__ unsigned short f2bf(float f) {
  unsigned u = __builtin_bit_cast(unsigned, f);
  u += 0x7fffu + ((u >> 16) & 1u);
  return (unsigned short)(u >> 16);
}

// two f32 -> packed 2x bf16 (hardware RNE)
__device__ __forceinline__ unsigned cvtpk(float lo, float hi) {
  unsigned r;
  asm("v_cvt_pk_bf16_f32 %0, %1, %2" : "=v"(r) : "v"(lo), "v"(hi));
  return r;
}

// packed f32x2 add (VOP3P)
__device__ __forceinline__ f32x2 pkadd(f32x2 a, f32x2 b) {
  f32x2 r;
  asm("v_pk_add_f32 %0, %1, %2" : "=v"(r) : "v"(a), "v"(b));
  return r;
}

// raw v_exp_f32: 2^x, single transcendental instruction (no libm wrapper)
__device__ __forceinline__ float fexp2(float x) {
  float r;
  asm("v_exp_f32 %0, %1" : "=v"(r) : "v"(x));
  return r;
}

__device__ __forceinline__ f32x4 mfma16(bf16x8 a, bf16x8 b, f32x4 c) {
  return __builtin_amdgcn_mfma_f32_16x16x32_bf16(a, b, c, 0, 0, 0);
}

__device__ __forceinline__ void gload_lds16(const void* g, void* l) {
  __builtin_amdgcn_global_load_lds(
      (const __attribute__((address_space(1))) void*)g,
      (__attribute__((address_space(3))) void*)l, 16, 0, 0);
}

// sizes
#define NQK 6291456      // 2*12*4096*64  (one z-slice of qkv, elems)
#define NX 6291456       // 8192*768      (one X tensor, elems)
#define NW 589824        // 768*768

// ---------------------------------------------------------------------------
// Kernel 1: prep = wtrans (blocks 0..431) + xconv (blocks 432..6575)
// ---------------------------------------------------------------------------
__global__ __launch_bounds__(256) void prep_kernel(
    const float* __restrict__ Wq, const float* __restrict__ Wk,
    const float* __restrict__ Wv, const float* __restrict__ from_t,
    const float* __restrict__ to_t, unsigned short* __restrict__ Wt,
    unsigned short* __restrict__ xb) {
  __shared__ float tile[64][65];
  const int bid = blockIdx.x;
  const int t = threadIdx.x;
  if (bid < 432) {
    const int z = bid / 144, rest = bid % 144;
    const float* __restrict__ src = (z == 0) ? Wq : (z == 1) ? Wk : Wv;
    unsigned short* __restrict__ dst = Wt + (size_t)z * NW;
    const int k0 = (rest / 12) * 64, n0 = (rest % 12) * 64;
    const int r = t >> 4, c4 = (t & 15) * 4;
#pragma unroll
    for (int p = 0; p < 4; ++p) {
      int rr = r + p * 16;
      f32x4 v = *(const f32x4*)(src + (size_t)(k0 + rr) * 768 + n0 + c4);
#pragma unroll
      for (int j = 0; j < 4; ++j) tile[rr][c4 + j] = v[j];
    }
    __syncthreads();
#pragma unroll
    for (int p = 0; p < 4; ++p) {
      int rn = r + p * 16;
      u16x4 o;
#pragma unroll
      for (int j = 0; j < 4; ++j) o[j] = f2bf(tile[c4 + j][rn]);
      *(u16x4*)(dst + (size_t)(n0 + rn) * 768 + k0 + c4) = o;
    }
  } else {
    const int idx = bid - 432;          // 0..6143
    const int y = idx / 3072, xi = idx % 3072;
    const float* __restrict__ src = y ? to_t : from_t;
    unsigned short* __restrict__ dst = xb + (size_t)y * NX;
    const size_t i = ((size_t)xi * 256 + t) * 8;
    f32x4 a = *(const f32x4*)(src + i);
    f32x4 b = *(const f32x4*)(src + i + 4);
    u16x8 o;
#pragma unroll
    for (int j = 0; j < 4; ++j) { o[j] = f2bf(a[j]); o[j + 4] = f2bf(b[j]); }
    *(u16x8*)(dst + i) = o;
  }
}

// ---------------------------------------------------------------------------
// Kernel 2: QKV projection, BK=64 double-buffered, raw barriers + counted
// vmcnt (no vmcnt(0) drain in steady state).  [R9/R11 proven structure]
// ---------------------------------------------------------------------------
__global__ __launch_bounds__(256) void qkv_gemm_kernel(
    const unsigned short* __restrict__ Xb, const unsigned short* __restrict__ Wt,
    const float* __restrict__ bq, const float* __restrict__ bk,
    const float* __restrict__ bv, unsigned short* __restrict__ qkvQK,
    unsigned short* __restrict__ vt, int zoff, int cpx) {
  __shared__ unsigned short A_lds[2][8192];  // [128m][64k] linear, src-swizzled
  __shared__ unsigned short B_lds[2][8192];  // [128n][64k]
  const int bid0 = blockIdx.x;
  const int bid = (bid0 & 7) * cpx + (bid0 >> 3);  // XCD-contiguous chunks
  const int z = zoff + bid / 384;
  const int rem = bid % 384;
  const int bm = rem / 6, bn = rem % 6;
  const unsigned short* __restrict__ X = Xb + (z ? (size_t)NX : 0);
  const unsigned short* __restrict__ Wz = Wt + (size_t)z * NW;
  const float* __restrict__ bias = (z == 0) ? bq : (z == 1) ? bk : bv;
  const int t = threadIdx.x, lane = t & 63, w = t >> 6;
  const int wm = (w >> 1) * 64, wn = (w & 1) * 64;
  const int l15 = lane & 15, cc = lane >> 4;

  f32x4 acc[4][4];
#pragma unroll
  for (int i = 0; i < 4; ++i)
#pragma unroll
    for (int j = 0; j < 4; ++j) acc[i][j] = (f32x4){0.f, 0.f, 0.f, 0.f};

  const unsigned short* Abase = X + (size_t)bm * 128 * 768;
  const unsigned short* Bbase = Wz + (size_t)bn * 128 * 768;

  auto STAGE = [&](int ks, int bufi) {
#pragma unroll
    for (int p = 0; p < 4; ++p) {
      int wb = p * 4 + w;            // wave-chunk 0..15 (wave-uniform)
      int ch = wb * 64 + lane;       // 16B chunk 0..1023
      int r = ch >> 3, sl = ch & 7;
      int g = sl ^ (r & 7);
      gload_lds16(Abase + (size_t)r * 768 + ks * 64 + g * 8,
                  &A_lds[bufi][wb * 512]);
      gload_lds16(Bbase + (size_t)r * 768 + ks * 64 + g * 8,
                  &B_lds[bufi][wb * 512]);
    }
  };

  STAGE(0, 0);

  for (int ks = 0; ks < 12; ++ks) {
    const int cur = ks & 1;
    if (ks < 11) {
      STAGE(ks + 1, cur ^ 1);
      asm volatile("s_waitcnt vmcnt(8)" ::: "memory");  // my tile-ks loads done
    } else {
      asm volatile("s_waitcnt vmcnt(0)" ::: "memory");
    }
    __builtin_amdgcn_s_barrier();  // whole tile visible, prev buffer free
    __builtin_amdgcn_sched_barrier(0);

    bf16x8 af[4][2], bfr[4][2];
#pragma unroll
    for (int mi = 0; mi < 4; ++mi) {
      int row = wm + mi * 16 + l15;
      const char* rp = (const char*)A_lds[cur] + row * 128;
#pragma unroll
      for (int kk = 0; kk < 2; ++kk)
        af[mi][kk] = *(const bf16x8*)(rp + (((cc + 4 * kk) ^ (row & 7)) << 4));
    }
#pragma unroll
    for (int ni = 0; ni < 4; ++ni) {
      int row = wn + ni * 16 + l15;
      const char* rp = (const char*)B_lds[cur] + row * 128;
#pragma unroll
      for (int kk = 0; kk < 2; ++kk)
        bfr[ni][kk] = *(const bf16x8*)(rp + (((cc + 4 * kk) ^ (row & 7)) << 4));
    }
#pragma unroll
    for (int kk = 0; kk < 2; ++kk)
#pragma unroll
      for (int mi = 0; mi < 4; ++mi)
#pragma unroll
        for (int ni = 0; ni < 4; ++ni)
          acc[mi][ni] = mfma16(af[mi][kk], bfr[ni][kk], acc[mi][ni]);
    // all waves done reading [cur] before anyone stages into it next iter
    asm volatile("s_waitcnt lgkmcnt(0)" ::: "memory");
    __builtin_amdgcn_s_barrier();
  }

  if (z < 2) {
    const float qscale = (z == 0) ? 0.125f * LOG2E : 1.0f;
    unsigned short* __restrict__ dst = qkvQK + (size_t)z * NQK;
#pragma unroll
    for (int ni = 0; ni < 4; ++ni) {
      int gn = bn * 128 + wn + ni * 16 + l15;
      float bv_ = bias[gn];
      int hh = gn >> 6, dd = gn & 63;
#pragma unroll
      for (int mi = 0; mi < 4; ++mi) {
#pragma unroll
        for (int r = 0; r < 4; ++r) {
          int gm = bm * 128 + wm + mi * 16 + cc * 4 + r;
          int bb = gm >> 12, s = gm & 4095;
          float val = (acc[mi][ni][r] + bv_) * qscale;
          dst[((((size_t)bb * 12 + hh) * 4096 + s) * 64) + dd] = f2bf(val);
        }
      }
    }
  } else {
    // V^T: vt[(bh*64+d)*4096 + s], r-index is s-contiguous -> packed stores
#pragma unroll
    for (int ni = 0; ni < 4; ++ni) {
      int gn = bn * 128 + wn + ni * 16 + l15;
      float bv_ = bias[gn];
      int hh = gn >> 6, dd = gn & 63;
#pragma unroll
      for (int mi = 0; mi < 4; ++mi) {
        int gm0 = bm * 128 + wm + mi * 16 + cc * 4;
        int bb = gm0 >> 12, s0 = gm0 & 4095;
        u16x4 o;
#pragma unroll
        for (int r = 0; r < 4; ++r) o[r] = f2bf(acc[mi][ni][r] + bv_);
        *(u16x4*)(vt + ((size_t)(bb * 12 + hh) * 64 + dd) * 4096 + s0) = o;
      }
    }
  }
}

// ---------------------------------------------------------------------------
// Kernel 3: block-sparse attention. R14 structure (raw v_exp_f32, penalty as
// MFMA C-in, permuted-key PV, software-pipelined QK(ib+1)).
// ---------------------------------------------------------------------------
__global__ __launch_bounds__(256, 4) void attn_kernel(
    const unsigned short* __restrict__ qkvQK, const unsigned short* __restrict__ vt,
    const int* __restrict__ to_mask, const int* __restrict__ rand_attn,
    float* __restrict__ out, float* __restrict__ part_o,
    float* __restrict__ part_ml) {
  __shared__ unsigned short K_lds[2][4096];   // [64key][64d], src-chunk swizzled
  __shared__ unsigned short VT_lds[2][4096];  // [64d][64key], src-chunk swizzled
  __shared__ float penal[8][64];
  __shared__ int blist[8];

  const int bid0 = blockIdx.x;
  const int bid = (bid0 & 7) * 234 + (bid0 >> 3);  // 234 = 3 (b,h)-groups/XCD
  const int bh = bid / 78, r78 = bid % 78;
  const int h = bh % 12, b = bh / 12;
  const int t = threadIdx.x, lane = t & 63, w = t >> 6;
  const int l15 = lane & 15, cc = lane >> 4;

  int m, nblk, chunk = 0;
  bool full;
  if (r78 < 62) {
    full = false;
    m = r78 + 1;
    nblk = (m == 1 || m == 62) ? 7 : 8;
    if (t == 0) {
      const int* rp = rand_attn + ((size_t)h * 62 + (m - 1)) * 3;
      if (m == 1) {
        blist[0] = 0; blist[1] = 1; blist[2] = 2; blist[3] = 63;
        blist[4] = rp[0]; blist[5] = rp[1]; blist[6] = rp[2];
      } else if (m == 62) {
        blist[0] = 0; blist[1] = 61; blist[2] = 62; blist[3] = 63;
        blist[4] = rp[0]; blist[5] = rp[1]; blist[6] = rp[2];
      } else {
        blist[0] = m - 1; blist[1] = m; blist[2] = m + 1;
        blist[3] = rp[0]; blist[4] = rp[1]; blist[5] = rp[2];
        blist[6] = 0; blist[7] = 63;
      }
    }
  } else {
    full = true;
    int fr = r78 - 62;
    chunk = fr & 7;
    m = (fr >> 3) ? 63 : 0;
    nblk = 8;
    if (t < 8) blist[t] = chunk * 8 + t;
  }

  const unsigned short* qp = qkvQK + (((size_t)b * 12 + h) * 4096 + m * 64) * 64;
  const unsigned short* kp = qkvQK + NQK + (((size_t)b * 12 + h) * 4096) * 64;
  const unsigned short* vtp = vt + (((size_t)b * 12 + h) * 64) * 4096;

  // hoisted per-lane staging constants
  int loff[2];
  const unsigned short *kpl[2], *vpl[2];
#pragma unroll
  for (int p = 0; p < 2; ++p) {
    int wb = p * 4 + w;            // wave-chunk (wave-uniform)
    int ch = wb * 64 + lane;       // 16B chunk id
    int rr = ch >> 3;
    int g = (ch & 7) ^ (rr & 7);   // source-chunk XOR permutation
    loff[p] = wb * 512;
    kpl[p] = kp + rr * 64 + g * 8;
    vpl[p] = vtp + rr * 4096 + g * 8;
  }

  // V^T b64 read base (bytes within one VT buffer), loop-invariant.
  int vaddr[4];
#pragma unroll
  for (int dg = 0; dg < 4; ++dg) {
    int d = dg * 16 + l15;
    vaddr[dg] = d * 128 + ((((cc >> 1) ^ (d & 7)) << 4)) + (cc & 1) * 8;
  }

  // Q as B-operand: col = q = l15, k = d  (log2e*0.125 folded in)
  bf16x8 aq[2];
  {
    int qrow = w * 16 + l15;
    aq[0] = *(const bf16x8*)(qp + qrow * 64 + cc * 8);
    aq[1] = *(const bf16x8*)(qp + qrow * 64 + 32 + cc * 8);
  }

  float m_run = -INFINITY, l_run = 0.f;  // per-lane state for q = w*16 + l15
  f32x4 o_acc[4];                        // q = cc*4+r, d = dg*16+l15
#pragma unroll
  for (int dg = 0; dg < 4; ++dg) o_acc[dg] = (f32x4){0.f, 0.f, 0.f, 0.f};

  auto STAGE_K = [&](int kb, int bufi) {
    const size_t ko = (size_t)kb * 4096;
    gload_lds16(kpl[0] + ko, &K_lds[bufi][loff[0]]);
    gload_lds16(kpl[1] + ko, &K_lds[bufi][loff[1]]);
  };
  auto STAGE_V = [&](int kb, int bufi) {
    const size_t vo = (size_t)kb * 64;
    gload_lds16(vpl[0] + vo, &VT_lds[bufi][loff[0]]);
    gload_lds16(vpl[1] + vo, &VT_lds[bufi][loff[1]]);
  };

  // QK of a tile (K in buffer bufi), penalty folded as MFMA C-in -> s[][]
  auto QK = [&](int bufi, int slot, float s[4][4]) {
    const char* kbase = (const char*)K_lds[bufi];
    __builtin_amdgcn_s_setprio(1);
#pragma unroll
    for (int kg = 0; kg < 4; ++kg) {
      int krow = kg * 16 + l15;
      const char* rp = kbase + krow * 128;
      int sz = (krow & 7) << 4;
      bf16x8 k0 = *(const bf16x8*)(rp + ((cc << 4) ^ sz));
      bf16x8 k1 = *(const bf16x8*)(rp + (((cc + 4) << 4) ^ sz));
      f32x4 pen = *(const f32x4*)(&penal[slot][kg * 16 + cc * 4]);
      f32x4 zz = mfma16(k0, aq[0], pen);  // C-in = penalty (S = K.Q + pen)
      zz = mfma16(k1, aq[1], zz);
#pragma unroll
      for (int r = 0; r < 4; ++r) s[kg][r] = zz[r];
    }
    __builtin_amdgcn_s_setprio(0);
  };

  __syncthreads();  // blist visible (no vmem in flight yet)

  {  // penal preload for the whole block list (log2e-scaled)
    int ib = w;
#pragma unroll
    for (int pp = 0; pp < 2; ++pp, ib += 4)
      if (ib < nblk)
        penal[ib][lane] =
            (1.0f - (float)to_mask[(size_t)b * 4096 + blist[ib] * 64 + lane]) *
            (-1e9f * LOG2E);
  }
  // prefetch: K0, V0, K1.  vmcnt(4): my K0 loads landed; lgkm: penal written.
  STAGE_K(blist[0], 0);
  STAGE_V(blist[0], 0);
  STAGE_K(blist[1], 1);
  asm volatile("s_waitcnt vmcnt(4) lgkmcnt(0)" ::: "memory");
  __builtin_amdgcn_s_barrier();  // everyone's K0 + penal visible
  __builtin_amdgcn_sched_barrier(0);

  float sm[4][4];
  QK(0, 0, sm);  // scores for tile 0 (in flight across loop-top barrier)

  union PF { unsigned u[4]; bf16x8 v; };
  union VF { u16x4 h2[2]; bf16x8 v; };

  for (int ib = 0; ib < nblk; ++ib) {
    // V(ib) and K(ib+1) were issued one full iteration ago -> wait is ~free
    asm volatile("s_waitcnt vmcnt(0)" ::: "memory");
    __builtin_amdgcn_s_barrier();
    __builtin_amdgcn_sched_barrier(0);

    // stage next tiles (after barrier -> buffers proven free)
    if (ib + 2 < nblk) STAGE_K(blist[ib + 2], ib & 1);
    if (ib + 1 < nblk) STAGE_V(blist[ib + 1], (ib + 1) & 1);

    // early QK for tile ib+1 (MFMA pipe; result consumed NEXT iteration)
    float sn[4][4];
    if (ib + 1 < nblk) QK((ib + 1) & 1, ib + 1, sn);

    // ---- softmax for tile ib (VALU pipe, overlaps QK retirement) ----
    float m1 = fmaxf(fmaxf(sm[0][0], sm[0][1]), sm[0][2]);
    float m2 = fmaxf(fmaxf(sm[0][3], sm[1][0]), sm[1][1]);
    float m3 = fmaxf(fmaxf(sm[1][2], sm[1][3]), sm[2][0]);
    float m4 = fmaxf(fmaxf(sm[2][1], sm[2][2]), sm[2][3]);
    float m5 = fmaxf(fmaxf(sm[3][0], sm[3][1]), sm[3][2]);
    float mx = fmaxf(fmaxf(fmaxf(m1, m2), m3),
                     fmaxf(fmaxf(m4, m5), sm[3][3]));
    mx = fmaxf(mx, __shfl_xor(mx, 16, 64));
    mx = fmaxf(mx, __shfl_xor(mx, 32, 64));

    // defer-max: rescale only when max grew by more than THR=8 (P <= 2^8)
    if (!__all(mx - m_run <= 8.0f)) {
      float mn = fmaxf(m_run, mx);
      float fac = fexp2(m_run - mn);
      m_run = mn;
      l_run *= fac;
      float fr_[4];
#pragma unroll
      for (int r = 0; r < 4; ++r) fr_[r] = __shfl(fac, cc * 4 + r, 64);
#pragma unroll
      for (int dg = 0; dg < 4; ++dg)
#pragma unroll
        for (int r = 0; r < 4; ++r) o_acc[dg][r] *= fr_[r];
    }

    // p = 2^(s - m) via raw v_exp_f32: pack + pk_add sum tree
    unsigned pk[8];
    f32x2 ps[8];
#pragma unroll
    for (int kg = 0; kg < 4; ++kg) {
      float p0 = fexp2(sm[kg][0] - m_run), p1 = fexp2(sm[kg][1] - m_run);
      float p2 = fexp2(sm[kg][2] - m_run), p3 = fexp2(sm[kg][3] - m_run);
      pk[kg * 2] = cvtpk(p0, p1);
      pk[kg * 2 + 1] = cvtpk(p2, p3);
      ps[kg * 2] = (f32x2){p0, p1};
      ps[kg * 2 + 1] = (f32x2){p2, p3};
    }
    f32x2 s0 = pkadd(pkadd(ps[0], ps[1]), pkadd(ps[2], ps[3]));
    f32x2 s1 = pkadd(pkadd(ps[4], ps[5]), pkadd(ps[6], ps[7]));
    f32x2 st = pkadd(s0, s1);
    float rs = st[0] + st[1];
    rs += __shfl_xor(rs, 16, 64);
    rs += __shfl_xor(rs, 32, 64);
    l_run += rs;

    // A-frags: permuted-key order => lane's own packs, no data movement
    PF a0, a1;
    a0.u[0] = pk[0]; a0.u[1] = pk[1]; a0.u[2] = pk[2]; a0.u[3] = pk[3];
    a1.u[0] = pk[4]; a1.u[1] = pk[5]; a1.u[2] = pk[6]; a1.u[3] = pk[7];

    // PV: V fragments via 4x ds_read_b64 per dg (same key permutation)
    const char* vbuf = (const char*)VT_lds[ib & 1];
    __builtin_amdgcn_s_setprio(1);
#pragma unroll
    for (int dg = 0; dg < 4; ++dg) {
      int a00 = vaddr[dg];
      VF f0, f1;
      f0.h2[0] = *(const u16x4*)(vbuf + a00);
      f0.h2[1] = *(const u16x4*)(vbuf + (a00 ^ 32));
      f1.h2[0] = *(const u16x4*)(vbuf + (a00 ^ 64));
      f1.h2[1] = *(const u16x4*)(vbuf + (a00 ^ 96));
      o_acc[dg] = mfma16(a0.v, f0.v, o_acc[dg]);
      o_acc[dg] = mfma16(a1.v, f1.v, o_acc[dg]);
    }
    __builtin_amdgcn_s_setprio(0);

    if (ib + 1 < nblk) {
#pragma unroll
      for (int kg = 0; kg < 4; ++kg)
#pragma unroll
        for (int r = 0; r < 4; ++r) sm[kg][r] = sn[kg][r];
    }
  }

  if (!full) {
    float inv[4];
#pragma unroll
    for (int r = 0; r < 4; ++r) inv[r] = 1.0f / __shfl(l_run, cc * 4 + r, 64);
#pragma unroll
    for (int r = 0; r < 4; ++r) {
      int s = m * 64 + w * 16 + cc * 4 + r;
#pragma unroll
      for (int dg = 0; dg < 4; ++dg) {
        int d = dg * 16 + l15;
        out[(((size_t)b * 4096 + s) * 12 + h) * 64 + d] = o_acc[dg][r] * inv[r];
      }
    }
  } else {
    const int row = (b * 12 + h) * 2 + (m ? 1 : 0);
    float* po = part_o + (((size_t)row * 8 + chunk) * 64) * 64;
    float* pml = part_ml + ((size_t)row * 8 + chunk) * 128;
#pragma unroll
    for (int r = 0; r < 4; ++r) {
      int q = w * 16 + cc * 4 + r;
#pragma unroll
      for (int dg = 0; dg < 4; ++dg) {
        int d = dg * 16 + l15;
        po[q * 64 + d] = o_acc[dg][r];
      }
    }
    if (cc == 0) {  // lane l15 holds softmax state (log2 domain) for its q
      pml[w * 16 + l15] = m_run;
      pml[64 + w * 16 + l15] = l_run;
    }
  }
}

// ---------------------------------------------------------------------------
// Kernel 4: merge 8 split-K partials per full row (48 rows), exp2 weights.
// ---------------------------------------------------------------------------
__global__ __launch_bounds__(256) void combine_kernel(
    const float* __restrict__ part_o, const float* __restrict__ part_ml,
    float* __restrict__ out) {
  const int row = blockIdx.x;  // (b*12+h)*2 + (m==63)
  const int b = row / 24, h = (row >> 1) % 12, m = (row & 1) ? 63 : 0;
  const int t = threadIdx.x;
  const int q = t >> 2, d0 = (t & 3) * 16;

  float mc[8], lc[8];
  float M = -INFINITY;
#pragma unroll
  for (int c = 0; c < 8; ++c) {
    const float* pml = part_ml + ((size_t)row * 8 + c) * 128;
    mc[c] = pml[q];
    lc[c] = pml[64 + q];
    M = fmaxf(M, mc[c]);
  }
  float wgt[8], L = 0.f;
#pragma unroll
  for (int c = 0; c < 8; ++c) {
    wgt[c] = fexp2(mc[c] - M);
    L += wgt[c] * lc[c];
  }
  f32x4 acc[4];
#pragma unroll
  for (int j = 0; j < 4; ++j) acc[j] = (f32x4){0.f, 0.f, 0.f, 0.f};
#pragma unroll
  for (int c = 0; c < 8; ++c) {
    const float* po = part_o + (((size_t)row * 8 + c) * 64 + q) * 64 + d0;
#pragma unroll
    for (int j = 0; j < 4; ++j) {
      f32x4 v = *(const f32x4*)(po + j * 4);
#pragma unroll
      for (int e = 0; e < 4; ++e) acc[j][e] += wgt[c] * v[e];
    }
  }
  const float inv = 1.0f / L;
  const int s = m * 64 + q;
  float* op = out + (((size_t)b * 4096 + s) * 12 + h) * 64 + d0;
#pragma unroll
  for (int j = 0; j < 4; ++j) {
    f32x4 v;
#pragma unroll
    for (int e = 0; e < 4; ++e) v[e] = acc[j][e] * inv;
    *(f32x4*)(op + j * 4) = v;
  }
}

// ---------------------------------------------------------------------------
extern "C" void kernel_launch(void* const* d_in, const int* in_sizes, int n_in,
                              void* d_out, int out_size, void* d_ws,
                              size_t ws_size, hipStream_t stream) {
  (void)in_sizes; (void)n_in; (void)out_size;
  const float* from_t = (const float*)d_in[0];
  const float* to_t = (const float*)d_in[1];
  const float* Wq = (const float*)d_in[2];
  const float* bq = (const float*)d_in[3];
  const float* Wk = (const float*)d_in[4];
  const float* bk = (const float*)d_in[5];
  const float* Wv = (const float*)d_in[6];
  const float* bv = (const float*)d_in[7];
  const int* to_mask = (const int*)d_in[8];
  const int* rand_attn = (const int*)d_in[9];
  float* out = (float*)d_out;

  unsigned short* Wt = (unsigned short*)d_ws;            // 3*NW bf16
  unsigned short* qkvQK = Wt + (size_t)3 * NW;           // 2*NQK bf16 (Q,K)
  unsigned short* Xb = qkvQK + (size_t)2 * NQK;          // 2*NX bf16

  const size_t part_elems = (size_t)48 * 8 * 64 * 64 + (size_t)48 * 8 * 128;
  const size_t fused_bytes =
      ((size_t)3 * NW + 2 * NQK + 2 * NX + NQK) * 2 + part_elems * 4;

  if (ws_size >= fused_bytes) {
    // vt in its own region; part overlays Xb (dead after the single gemm)
    unsigned short* vt = Xb + (size_t)2 * NX;
    float* part_o = (float*)Xb;
    float* part_ml = part_o + (size_t)48 * 8 * 64 * 64;

    prep_kernel<<<dim3(6576), dim3(256), 0, stream>>>(Wq, Wk, Wv, from_t, to_t,
                                                      Wt, Xb);
    qkv_gemm_kernel<<<dim3(1152), dim3(256), 0, stream>>>(
        Xb, Wt, bq, bk, bv, qkvQK, vt, 0, 144);  // z=0,1,2 fused
    attn_kernel<<<dim3(1872), dim3(256), 0, stream>>>(
        qkvQK, vt, to_mask, rand_attn, out, part_o, part_ml);
    combine_kernel<<<dim3(48), dim3(256), 0, stream>>>(part_o, part_ml, out);
  } else {
    // fallback (53.9 MB): vt overlays Xb[0], parts overlay Xb[1]
    unsigned short* vt = Xb;
    float* part_o = (float*)(Xb + (size_t)NX);
    float* part_ml = part_o + (size_t)48 * 8 * 64 * 64;

    prep_kernel<<<dim3(6576), dim3(256), 0, stream>>>(Wq, Wk, Wv, from_t, to_t,
                                                      Wt, Xb);
    qkv_gemm_kernel<<<dim3(768), dim3(256), 0, stream>>>(
        Xb, Wt, bq, bk, bv, qkvQK, vt, 0, 96);   // z=0,1 (Q,K)
    qkv_gemm_kernel<<<dim3(384), dim3(256), 0, stream>>>(
        Xb, Wt, bq, bk, bv, qkvQK, vt, 2, 48);   // z=2 (V^T)
    attn_kernel<<<dim3(1872), dim3(256), 0, stream>>>(
        qkvQK, vt, to_mask, rand_attn, out, part_o, part_ml);
    combine_kernel<<<dim3(48), dim3(256), 0, stream>>>(part_o, part_ml, out);
  }
}